// Round 8
// baseline (2751.259 us; speedup 1.0000x reference)
//
#include <hip/hip_runtime.h>
#include <hip/hip_bf16.h>

// Problem constants
#define BATCH 8
#define NTOK 4096
#define IN_DIM 768
#define NHEAD 12
#define DH 64
#define D_MODEL 768          // NHEAD*DH
#define OC 2304              // 3*D_MODEL, qkv row stride
#define SCALE 0.125f         // DH^-0.5

typedef _Float16 f16x8 __attribute__((ext_vector_type(8)));
typedef _Float16 f16x4 __attribute__((ext_vector_type(4)));
typedef float f32x4 __attribute__((ext_vector_type(4)));

// global -> LDS direct DMA, 16B per lane (dest = wave-uniform base + lane*16)
__device__ __forceinline__ void gload16(const void* g, void* l)
{
    __builtin_amdgcn_global_load_lds(
        (const __attribute__((address_space(1))) void*)g,
        (__attribute__((address_space(3))) void*)l, 16, 0, 0);
}

// ---------------- fp32 -> (hi,lo) f16 split, vectorized ----------------
__global__ __launch_bounds__(256)
void split_f32_kernel(const float* __restrict__ in, _Float16* __restrict__ hi,
                      _Float16* __restrict__ lo, int n4)   // n4 = n/4
{
    int i = blockIdx.x * 256 + threadIdx.x;
    const int stride = gridDim.x * 256;
    for (; i < n4; i += stride) {
        float4 v = ((const float4*)in)[i];
        float f[4] = {v.x, v.y, v.z, v.w};
        f16x4 h, l;
#pragma unroll
        for (int e = 0; e < 4; ++e) {
            _Float16 hh = (_Float16)f[e];
            h[e] = hh;
            l[e] = (_Float16)(f[e] - (float)hh);
        }
        ((f16x4*)hi)[i] = h;
        ((f16x4*)lo)[i] = l;
    }
}

// ---------------- split-f16 MFMA GEMM:  C = A @ W^T (+bias) ----------------
// A given as (Ah,Al) f16 [M,K] row-major, W as (Wh,Wl) f16 [Nout,K] row-major.
// 3-product split (hi*hi + hi*lo + lo*hi) ~ fp32 accuracy.
// 128x128 tile, BK=32, 4 waves (2x2), per-wave 64x64 = 4x4 frags of 16x16x32.
// Staging via global_load_lds (16B/lane DMA), fragment-major LDS.
// Grid is 1D = (Nout/128)*32, M must be 4096 (32 bm tiles).
// XCD-chunked swizzle (round-7 fix for 4x HBM over-fetch, FETCH 77MB vs 20MB
// compulsory): xcd = bid&7 owns 4 contiguous bm rows; consecutive blocks on
// an XCD share one W panel -> per-XCD L2 resident set ~2MB < 4MB.
template<bool BIAS>
__global__ __launch_bounds__(256, 3)
void gemm_nt_f16pair(const _Float16* __restrict__ Ahg, const _Float16* __restrict__ Alg,
                     const _Float16* __restrict__ Whg, const _Float16* __restrict__ Wlg,
                     const float* __restrict__ bias, float* __restrict__ C,
                     int M, int K, int Nout)
{
    __shared__ f16x8 Ah[512], Al[512], Wh[512], Wl[512];   // 8 KB each = 32 KB
    const int tid  = threadIdx.x;
    const int lane = tid & 63;
    const int wave = tid >> 6;
    const int wm = wave >> 1, wn = wave & 1;

    const int bid = blockIdx.x;
    const int xcd = bid & 7;
    const int idx = bid >> 3;
    const int bm = (xcd * 4 + (idx & 3)) * 128;   // 32 bm tiles, 4 per XCD
    const int bn = (idx >> 2) * 128;

    // per-lane global offsets for payloads p0 = wave*64+lane, p1 = p0+256
    // payload p: row = (p>>6)*16 + (lane&15), k-cols 8*(lane>>4)..+7
    const int r0 = wave * 16 + (lane & 15);
    const int ko = 8 * (lane >> 4);
    const size_t aoff0 = (size_t)(bm + r0) * K + ko;
    const size_t aoff1 = aoff0 + (size_t)64 * K;
    const size_t woff0 = (size_t)(bn + r0) * K + ko;
    const size_t woff1 = woff0 + (size_t)64 * K;

    f32x4 acc[4][4] = {};

    for (int k0 = 0; k0 < K; k0 += 32) {
        gload16(Ahg + aoff0 + k0, &Ah[wave * 64]);
        gload16(Ahg + aoff1 + k0, &Ah[wave * 64 + 256]);
        gload16(Alg + aoff0 + k0, &Al[wave * 64]);
        gload16(Alg + aoff1 + k0, &Al[wave * 64 + 256]);
        gload16(Whg + woff0 + k0, &Wh[wave * 64]);
        gload16(Whg + woff1 + k0, &Wh[wave * 64 + 256]);
        gload16(Wlg + woff0 + k0, &Wl[wave * 64]);
        gload16(Wlg + woff1 + k0, &Wl[wave * 64 + 256]);
        __syncthreads();   // drains vmcnt -> LDS tiles complete

        f16x8 a_h[4], a_l[4], w_h[4], w_l[4];
#pragma unroll
        for (int i = 0; i < 4; ++i) {
            a_h[i] = Ah[(wm * 4 + i) * 64 + lane];
            a_l[i] = Al[(wm * 4 + i) * 64 + lane];
            w_h[i] = Wh[(wn * 4 + i) * 64 + lane];
            w_l[i] = Wl[(wn * 4 + i) * 64 + lane];
        }

#pragma unroll
        for (int i = 0; i < 4; ++i)
#pragma unroll
            for (int j = 0; j < 4; ++j) {
                acc[i][j] = __builtin_amdgcn_mfma_f32_16x16x32_f16(a_h[i], w_h[j], acc[i][j], 0, 0, 0);
                acc[i][j] = __builtin_amdgcn_mfma_f32_16x16x32_f16(a_h[i], w_l[j], acc[i][j], 0, 0, 0);
                acc[i][j] = __builtin_amdgcn_mfma_f32_16x16x32_f16(a_l[i], w_h[j], acc[i][j], 0, 0, 0);
            }
        __syncthreads();
    }

    // ---- epilogue: C/D layout col=lane&15, row=(lane>>4)*4+reg
    const int r4 = (lane >> 4) * 4;
    const int cc = lane & 15;
#pragma unroll
    for (int i = 0; i < 4; ++i) {
        int grow = bm + (wm * 4 + i) * 16 + r4;
#pragma unroll
        for (int j = 0; j < 4; ++j) {
            int gcol = bn + (wn * 4 + j) * 16 + cc;
            float badd = BIAS ? bias[gcol] : 0.f;
#pragma unroll
            for (int r = 0; r < 4; ++r)
                C[(size_t)(grow + r) * Nout + gcol] = acc[i][j][r] + badd;
        }
    }
}

// ---------------- fused: ctx'[h][d][e] += sum_n exp(k[n,d]) * v[n,e]
//                          colsum[h*64+d] += sum_n exp(k[n,d])
// k values ~N(0, 0.55^2) -> exp() cannot overflow; no max-subtraction needed.
// NCH=64 (round-7 fix: 16 -> 192 blocks = 0.75/CU; 64 -> 768 blocks = 3/CU)
#define NCH 64
__global__ __launch_bounds__(256)
void context_kernel(const float* __restrict__ qkv_b, float* __restrict__ ctx,
                    float* __restrict__ colsum)
{
    const int h = blockIdx.x;             // 0..11
    const int n0 = blockIdx.y * (NTOK / NCH);
    const int t = threadIdx.x;
    const int d = t & 63, eb = t >> 6;    // eb 0..3
    const float* kb = qkv_b + h * 192 + 64;
    const float* vb = kb + 64;
    __shared__ float Ks[16][64];
    __shared__ float Vs[16][64];

    float acc[16];
#pragma unroll
    for (int j = 0; j < 16; ++j) acc[j] = 0.f;
    float psum = 0.f;

    const int r = t >> 4, c4 = t & 15;
    for (int nc = 0; nc < NTOK / NCH; nc += 16) {
        const size_t off = (size_t)(n0 + nc + r) * OC + c4 * 4;
        *(float4*)&Ks[r][c4 * 4] = *(const float4*)(kb + off);
        *(float4*)&Vs[r][c4 * 4] = *(const float4*)(vb + off);
        __syncthreads();
#pragma unroll
        for (int nn = 0; nn < 16; ++nn) {
            float p = __expf(Ks[nn][d]);
            psum += p;
#pragma unroll
            for (int j = 0; j < 16; ++j)
                acc[j] = fmaf(p, Vs[nn][eb * 16 + j], acc[j]);
        }
        __syncthreads();
    }
    float* cp = ctx + ((size_t)h * 64 + d) * 64 + eb * 16;
#pragma unroll
    for (int j = 0; j < 16; ++j) atomicAdd(cp + j, acc[j]);
    if (eb == 0) atomicAdd(colsum + h * 64 + d, psum);
}

// ---------------- qs[row, h*64+d] = softmax_d(q[row,h,:]) * SCALE -> split f16
__global__ __launch_bounds__(256)
void qsoftmax_kernel(const float* __restrict__ qkv_b,
                     _Float16* __restrict__ qsh, _Float16* __restrict__ qsl)
{
    const size_t row = blockIdx.x;       // 0..N-1
    const int t = threadIdx.x;
    const int hq = t >> 6;               // wave id 0..3
    const int d = t & 63;
    const float* qrow = qkv_b + row * OC;
#pragma unroll
    for (int hg = 0; hg < NHEAD; hg += 4) {
        int h = hg + hq;
        float v = qrow[h * 192 + d];
        float m = v;
#pragma unroll
        for (int off = 32; off >= 1; off >>= 1) m = fmaxf(m, __shfl_xor(m, off));
        float e = __expf(v - m);
        float s = e;
#pragma unroll
        for (int off = 32; off >= 1; off >>= 1) s += __shfl_xor(s, off);
        float val = e / s * SCALE;
        _Float16 hh = (_Float16)val;
        size_t idx = row * D_MODEL + h * 64 + d;
        qsh[idx] = hh;
        qsl[idx] = (_Float16)(val - (float)hh);
    }
}

// ---------------- MT[o][h*64+d] = sum_e (ctx'[h,d,e]/colsum[h*64+d]) * w_lin[o, h*64+e]
// grid (NHEAD, D_MODEL/64) = 144 blocks; 64x64 tile per block; split-f16 out.
__global__ __launch_bounds__(256)
void mt_kernel(const float* __restrict__ ctx, const float* __restrict__ colsum,
               const float* __restrict__ wlin,
               _Float16* __restrict__ MTh, _Float16* __restrict__ MTl)
{
    const int h = blockIdx.x;            // 0..11
    const int o0 = blockIdx.y * 64;      // output-row tile
    const int t = threadIdx.x;
    const int d = t & 63, og = t >> 6;   // og 0..3
    __shared__ float cs[64][65];         // normalized ctx (2-way = free)
    __shared__ float wl[64][65];         // w_lin tile
    __shared__ float inv_s[64];
    if (t < 64) inv_s[t] = 1.f / colsum[h * 64 + t];
    __syncthreads();
    for (int i = t; i < 4096; i += 256)
        cs[i >> 6][i & 63] = ctx[(size_t)h * 4096 + i] * inv_s[i >> 6];
#pragma unroll
    for (int j = 0; j < 4; ++j) {
        int idx = t + j * 256;           // 0..1023
        int r = idx >> 4, c4 = idx & 15; // full 64x64 coverage
        float4 v = *(const float4*)(wlin + (size_t)(o0 + r) * D_MODEL + h * 64 + c4 * 4);
        wl[r][c4 * 4 + 0] = v.x; wl[r][c4 * 4 + 1] = v.y;
        wl[r][c4 * 4 + 2] = v.z; wl[r][c4 * 4 + 3] = v.w;
    }
    __syncthreads();
#pragma unroll
    for (int oo = 0; oo < 16; ++oo) {
        int o = og * 16 + oo;            // wl[o][*] is wave-uniform -> broadcast
        float s = 0.f;
#pragma unroll
        for (int e = 0; e < 64; ++e)
            s = fmaf(wl[o][e], cs[d][e], s);
        _Float16 hh = (_Float16)s;
        size_t idx = (size_t)(o0 + o) * D_MODEL + h * 64 + d;
        MTh[idx] = hh;
        MTl[idx] = (_Float16)(s - (float)hh);
    }
}

extern "C" void kernel_launch(void* const* d_in, const int* in_sizes, int n_in,
                              void* d_out, int out_size, void* d_ws, size_t ws_size,
                              hipStream_t stream)
{
    const float* x     = (const float*)d_in[0];   // [B,N,768]
    const float* w_qkv = (const float*)d_in[1];   // [2304,768]
    const float* w_lin = (const float*)d_in[2];   // [768,768]
    const float* b_lin = (const float*)d_in[3];   // [768]
    float* out = (float*)d_out;                   // [B,N,768]

    // Workspace (~61 MB; proven safe in round 7).
    float* ws      = (float*)d_ws;
    float* qkv_b   = ws;                                        // 9,437,184 f32
    float* ctx_all = qkv_b + (size_t)NTOK * OC;                 //   393,216 f32
    float* sum_all = ctx_all + (size_t)BATCH * NHEAD * DH * DH; //     6,144 f32
    _Float16* wqh  = (_Float16*)(sum_all + (size_t)BATCH * D_MODEL);
    _Float16* wql  = wqh + (size_t)OC * IN_DIM;                 // 1,769,472 f16 each
    _Float16* xh   = wql + (size_t)OC * IN_DIM;                 // 3,145,728 f16 each
    _Float16* xl   = xh + (size_t)NTOK * IN_DIM;
    _Float16* MTh  = xl + (size_t)NTOK * IN_DIM;                //   589,824 f16 each
    _Float16* MTl  = MTh + (size_t)D_MODEL * D_MODEL;
    // qs pair aliases x pair (x is dead after GEMM1 within each batch iter)
    _Float16* qsh = xh;
    _Float16* qsl = xl;

    hipMemsetAsync(ctx_all, 0,
                   ((size_t)BATCH * NHEAD * DH * DH + BATCH * D_MODEL) * sizeof(float),
                   stream);

    // w_qkv split once per call
    split_f32_kernel<<<(OC * IN_DIM / 4 + 255) / 256, 256, 0, stream>>>(
        w_qkv, wqh, wql, OC * IN_DIM / 4);

    for (int b = 0; b < BATCH; ++b) {
        const float* x_b = x + (size_t)b * NTOK * IN_DIM;
        float* ctx_b = ctx_all + (size_t)b * NHEAD * DH * DH;
        float* sum_b = sum_all + (size_t)b * D_MODEL;
        float* out_b = out + (size_t)b * NTOK * D_MODEL;

        // 0) split x_b into f16 hi/lo
        split_f32_kernel<<<2048, 256, 0, stream>>>(x_b, xh, xl, NTOK * IN_DIM / 4);

        // 1) qkv_b = x_b @ w_qkv^T  [4096,2304]  (split-f16 MFMA, XCD-swizzled 1D grid)
        gemm_nt_f16pair<false><<<(OC / 128) * 32, 256, 0, stream>>>(
            xh, xl, wqh, wql, nullptr, qkv_b, NTOK, IN_DIM, OC);

        // 2) fused unnormalized context + column sums (no-max softmax: k is O(1))
        dim3 g2(NHEAD, NCH);
        context_kernel<<<g2, 256, 0, stream>>>(qkv_b, ctx_b, sum_b);

        // 3) qs = rowwise softmax(q) * SCALE  -> split f16 (overwrites x pair)
        qsoftmax_kernel<<<NTOK, 256, 0, stream>>>(qkv_b, qsh, qsl);

        // 4) MT[o][hd] = sum_e (ctx/colsum) * w_lin  (folds o-projection), split f16
        dim3 g4(NHEAD, D_MODEL / 64);
        mt_kernel<<<g4, 256, 0, stream>>>(ctx_b, sum_b, w_lin, MTh, MTl);

        // 5) out_b = qs @ MT^T + b_lin  [4096,768]  (split-f16 MFMA, swizzled)
        gemm_nt_f16pair<true><<<(D_MODEL / 128) * 32, 256, 0, stream>>>(
            qsh, qsl, MTh, MTl, b_lin, out_b, NTOK, D_MODEL, D_MODEL);
    }
}

// Round 9
// 1625.035 us; speedup vs baseline: 1.6930x; 1.6930x over previous
//
#include <hip/hip_runtime.h>
#include <hip/hip_bf16.h>

// Problem constants
#define BATCH 8
#define NTOK 4096
#define IN_DIM 768
#define NHEAD 12
#define DH 64
#define D_MODEL 768          // NHEAD*DH
#define OC 2304              // 3*D_MODEL, qkv row stride
#define SCALE 0.125f         // DH^-0.5
#define NCH 32               // context chunks (partials, no atomics)

typedef _Float16 f16x8 __attribute__((ext_vector_type(8)));
typedef _Float16 f16x4 __attribute__((ext_vector_type(4)));
typedef float f32x4 __attribute__((ext_vector_type(4)));

// global -> LDS direct DMA, 16B per lane (dest = wave-uniform base + lane*16)
__device__ __forceinline__ void gload16(const void* g, void* l)
{
    __builtin_amdgcn_global_load_lds(
        (const __attribute__((address_space(1))) void*)g,
        (__attribute__((address_space(3))) void*)l, 16, 0, 0);
}

// ---------------- fp32 -> (hi,lo) f16 split, vectorized ----------------
__global__ __launch_bounds__(256)
void split_f32_kernel(const float* __restrict__ in, _Float16* __restrict__ hi,
                      _Float16* __restrict__ lo, int n4)   // n4 = n/4
{
    int i = blockIdx.x * 256 + threadIdx.x;
    const int stride = gridDim.x * 256;
    for (; i < n4; i += stride) {
        float4 v = ((const float4*)in)[i];
        float f[4] = {v.x, v.y, v.z, v.w};
        f16x4 h, l;
#pragma unroll
        for (int e = 0; e < 4; ++e) {
            _Float16 hh = (_Float16)f[e];
            h[e] = hh;
            l[e] = (_Float16)(f[e] - (float)hh);
        }
        ((f16x4*)hi)[i] = h;
        ((f16x4*)lo)[i] = l;
    }
}

// ---------------- split-f16 MFMA GEMM:  C = A @ W^T (+bias) ----------------
// A given as (Ah,Al) f16 [M,K] row-major, W as (Wh,Wl) f16 [Nout,K] row-major.
// 3-product split (hi*hi + hi*lo + lo*hi) ~ fp32 accuracy.
// 128x128 tile, BK=32, 4 waves (2x2), per-wave 64x64 = 4x4 frags of 16x16x32.
// Staging via global_load_lds (16B/lane DMA), fragment-major LDS.
// Grid is 1D = (Nout/128)*32, M must be 4096 (32 bm tiles).
// XCD-chunked swizzle: xcd = bid&7 owns 4 contiguous bm rows; consecutive
// blocks on an XCD share one W panel -> per-XCD L2 resident set ~2MB < 4MB.
template<bool BIAS>
__global__ __launch_bounds__(256, 3)
void gemm_nt_f16pair(const _Float16* __restrict__ Ahg, const _Float16* __restrict__ Alg,
                     const _Float16* __restrict__ Whg, const _Float16* __restrict__ Wlg,
                     const float* __restrict__ bias, float* __restrict__ C,
                     int M, int K, int Nout)
{
    __shared__ f16x8 Ah[512], Al[512], Wh[512], Wl[512];   // 8 KB each = 32 KB
    const int tid  = threadIdx.x;
    const int lane = tid & 63;
    const int wave = tid >> 6;
    const int wm = wave >> 1, wn = wave & 1;

    const int bid = blockIdx.x;
    const int xcd = bid & 7;
    const int idx = bid >> 3;
    const int bm = (xcd * 4 + (idx & 3)) * 128;   // 32 bm tiles, 4 per XCD
    const int bn = (idx >> 2) * 128;

    // per-lane global offsets for payloads p0 = wave*64+lane, p1 = p0+256
    // payload p: row = (p>>6)*16 + (lane&15), k-cols 8*(lane>>4)..+7
    const int r0 = wave * 16 + (lane & 15);
    const int ko = 8 * (lane >> 4);
    const size_t aoff0 = (size_t)(bm + r0) * K + ko;
    const size_t aoff1 = aoff0 + (size_t)64 * K;
    const size_t woff0 = (size_t)(bn + r0) * K + ko;
    const size_t woff1 = woff0 + (size_t)64 * K;

    f32x4 acc[4][4] = {};

    for (int k0 = 0; k0 < K; k0 += 32) {
        gload16(Ahg + aoff0 + k0, &Ah[wave * 64]);
        gload16(Ahg + aoff1 + k0, &Ah[wave * 64 + 256]);
        gload16(Alg + aoff0 + k0, &Al[wave * 64]);
        gload16(Alg + aoff1 + k0, &Al[wave * 64 + 256]);
        gload16(Whg + woff0 + k0, &Wh[wave * 64]);
        gload16(Whg + woff1 + k0, &Wh[wave * 64 + 256]);
        gload16(Wlg + woff0 + k0, &Wl[wave * 64]);
        gload16(Wlg + woff1 + k0, &Wl[wave * 64 + 256]);
        __syncthreads();   // drains vmcnt -> LDS tiles complete

        f16x8 a_h[4], a_l[4], w_h[4], w_l[4];
#pragma unroll
        for (int i = 0; i < 4; ++i) {
            a_h[i] = Ah[(wm * 4 + i) * 64 + lane];
            a_l[i] = Al[(wm * 4 + i) * 64 + lane];
            w_h[i] = Wh[(wn * 4 + i) * 64 + lane];
            w_l[i] = Wl[(wn * 4 + i) * 64 + lane];
        }

#pragma unroll
        for (int i = 0; i < 4; ++i)
#pragma unroll
            for (int j = 0; j < 4; ++j) {
                acc[i][j] = __builtin_amdgcn_mfma_f32_16x16x32_f16(a_h[i], w_h[j], acc[i][j], 0, 0, 0);
                acc[i][j] = __builtin_amdgcn_mfma_f32_16x16x32_f16(a_h[i], w_l[j], acc[i][j], 0, 0, 0);
                acc[i][j] = __builtin_amdgcn_mfma_f32_16x16x32_f16(a_l[i], w_h[j], acc[i][j], 0, 0, 0);
            }
        __syncthreads();
    }

    // ---- epilogue: C/D layout col=lane&15, row=(lane>>4)*4+reg
    const int r4 = (lane >> 4) * 4;
    const int cc = lane & 15;
#pragma unroll
    for (int i = 0; i < 4; ++i) {
        int grow = bm + (wm * 4 + i) * 16 + r4;
#pragma unroll
        for (int j = 0; j < 4; ++j) {
            int gcol = bn + (wn * 4 + j) * 16 + cc;
            float badd = BIAS ? bias[gcol] : 0.f;
#pragma unroll
            for (int r = 0; r < 4; ++r)
                C[(size_t)(grow + r) * Nout + gcol] = acc[i][j][r] + badd;
        }
    }
}

// ---------------- partial context: ctxp[ch][h][d][e] = sum_{n in chunk} exp(k[n,d]) v[n,e]
//                  csp[ch][h*64+d]  = sum_{n in chunk} exp(k[n,d])
// Plain stores to private slices (round-8 fix: atomicAdd finalization caused
// 98MB WRITE_SIZE of L2 RMW contention, 167us/dispatch).
// k values ~N(0, 0.55^2) -> exp() cannot overflow; no max-subtraction needed.
__global__ __launch_bounds__(256)
void context_kernel(const float* __restrict__ qkv_b, float* __restrict__ ctxp,
                    float* __restrict__ csp)
{
    const int h = blockIdx.x;             // 0..11
    const int ch = blockIdx.y;            // 0..NCH-1
    const int n0 = ch * (NTOK / NCH);
    const int t = threadIdx.x;
    const int d = t & 63, eb = t >> 6;    // eb 0..3
    const float* kb = qkv_b + h * 192 + 64;
    const float* vb = kb + 64;
    __shared__ float Ks[16][64];
    __shared__ float Vs[16][64];

    float acc[16];
#pragma unroll
    for (int j = 0; j < 16; ++j) acc[j] = 0.f;
    float psum = 0.f;

    const int r = t >> 4, c4 = t & 15;
    for (int nc = 0; nc < NTOK / NCH; nc += 16) {
        const size_t off = (size_t)(n0 + nc + r) * OC + c4 * 4;
        *(float4*)&Ks[r][c4 * 4] = *(const float4*)(kb + off);
        *(float4*)&Vs[r][c4 * 4] = *(const float4*)(vb + off);
        __syncthreads();
#pragma unroll
        for (int nn = 0; nn < 16; ++nn) {
            float p = __expf(Ks[nn][d]);
            psum += p;
#pragma unroll
            for (int j = 0; j < 16; ++j)
                acc[j] = fmaf(p, Vs[nn][eb * 16 + j], acc[j]);
        }
        __syncthreads();
    }
    float* cp = ctxp + (((size_t)ch * NHEAD + h) * 64 + d) * 64 + eb * 16;
#pragma unroll
    for (int j = 0; j < 16; ++j) cp[j] = acc[j];
    if (eb == 0) csp[(size_t)ch * D_MODEL + h * 64 + d] = psum;
}

// ---------------- ctx[i] = sum_ch ctxp[ch][i]   (i over 12*64*64) ----------------
__global__ __launch_bounds__(256)
void reduce_ctx_kernel(const float* __restrict__ ctxp, float* __restrict__ ctx)
{
    const int i = blockIdx.x * 256 + threadIdx.x;   // 0..49151
    float s = 0.f;
#pragma unroll
    for (int ch = 0; ch < NCH; ++ch)
        s += ctxp[(size_t)ch * (NHEAD * DH * DH) + i];
    ctx[i] = s;
}

// ---------------- qs[row, h*64+d] = softmax_d(q[row,h,:]) * SCALE -> split f16
__global__ __launch_bounds__(256)
void qsoftmax_kernel(const float* __restrict__ qkv_b,
                     _Float16* __restrict__ qsh, _Float16* __restrict__ qsl)
{
    const size_t row = blockIdx.x;       // 0..N-1
    const int t = threadIdx.x;
    const int hq = t >> 6;               // wave id 0..3
    const int d = t & 63;
    const float* qrow = qkv_b + row * OC;
#pragma unroll
    for (int hg = 0; hg < NHEAD; hg += 4) {
        int h = hg + hq;
        float v = qrow[h * 192 + d];
        float m = v;
#pragma unroll
        for (int off = 32; off >= 1; off >>= 1) m = fmaxf(m, __shfl_xor(m, off));
        float e = __expf(v - m);
        float s = e;
#pragma unroll
        for (int off = 32; off >= 1; off >>= 1) s += __shfl_xor(s, off);
        float val = e / s * SCALE;
        _Float16 hh = (_Float16)val;
        size_t idx = row * D_MODEL + h * 64 + d;
        qsh[idx] = hh;
        qsl[idx] = (_Float16)(val - (float)hh);
    }
}

// ---------------- MT[o][h*64+d] = sum_e (ctx[h,d,e]/colsum[h*64+d]) * w_lin[o, h*64+e]
// grid (NHEAD, D_MODEL/64) = 144 blocks; 64x64 tile per block; split-f16 out.
// colsum = sum of csp partials (summed here, 32 L2 reads per d).
__global__ __launch_bounds__(256)
void mt_kernel(const float* __restrict__ ctx, const float* __restrict__ csp,
               const float* __restrict__ wlin,
               _Float16* __restrict__ MTh, _Float16* __restrict__ MTl)
{
    const int h = blockIdx.x;            // 0..11
    const int o0 = blockIdx.y * 64;      // output-row tile
    const int t = threadIdx.x;
    const int d = t & 63, og = t >> 6;   // og 0..3
    __shared__ float cs[64][65];         // normalized ctx (2-way = free)
    __shared__ float wl[64][65];         // w_lin tile
    __shared__ float inv_s[64];
    if (t < 64) {
        float s = 0.f;
#pragma unroll
        for (int ch = 0; ch < NCH; ++ch)
            s += csp[(size_t)ch * D_MODEL + h * 64 + t];
        inv_s[t] = 1.f / s;
    }
    __syncthreads();
    for (int i = t; i < 4096; i += 256)
        cs[i >> 6][i & 63] = ctx[(size_t)h * 4096 + i] * inv_s[i >> 6];
#pragma unroll
    for (int j = 0; j < 4; ++j) {
        int idx = t + j * 256;           // 0..1023
        int r = idx >> 4, c4 = idx & 15; // full 64x64 coverage
        float4 v = *(const float4*)(wlin + (size_t)(o0 + r) * D_MODEL + h * 64 + c4 * 4);
        wl[r][c4 * 4 + 0] = v.x; wl[r][c4 * 4 + 1] = v.y;
        wl[r][c4 * 4 + 2] = v.z; wl[r][c4 * 4 + 3] = v.w;
    }
    __syncthreads();
#pragma unroll
    for (int oo = 0; oo < 16; ++oo) {
        int o = og * 16 + oo;            // wl[o][*] is wave-uniform -> broadcast
        float s = 0.f;
#pragma unroll
        for (int e = 0; e < 64; ++e)
            s = fmaf(wl[o][e], cs[d][e], s);
        _Float16 hh = (_Float16)s;
        size_t idx = (size_t)(o0 + o) * D_MODEL + h * 64 + d;
        MTh[idx] = hh;
        MTl[idx] = (_Float16)(s - (float)hh);
    }
}

extern "C" void kernel_launch(void* const* d_in, const int* in_sizes, int n_in,
                              void* d_out, int out_size, void* d_ws, size_t ws_size,
                              hipStream_t stream)
{
    const float* x     = (const float*)d_in[0];   // [B,N,768]
    const float* w_qkv = (const float*)d_in[1];   // [2304,768]
    const float* w_lin = (const float*)d_in[2];   // [768,768]
    const float* b_lin = (const float*)d_in[3];   // [768]
    float* out = (float*)d_out;                   // [B,N,768]

    // Workspace (~66 MB).
    float* ws     = (float*)d_ws;
    float* qkv_b  = ws;                                        // 9,437,184 f32
    float* ctxp   = qkv_b + (size_t)NTOK * OC;                 // NCH*12*64*64 = 1,572,864
    float* csp    = ctxp + (size_t)NCH * NHEAD * DH * DH;      // NCH*768 = 24,576
    float* ctx_s  = csp + (size_t)NCH * D_MODEL;               // 49,152
    _Float16* wqh = (_Float16*)(ctx_s + (size_t)NHEAD * DH * DH);
    _Float16* wql = wqh + (size_t)OC * IN_DIM;                 // 1,769,472 f16 each
    _Float16* xh  = wql + (size_t)OC * IN_DIM;                 // 3,145,728 f16 each
    _Float16* xl  = xh + (size_t)NTOK * IN_DIM;
    _Float16* MTh = xl + (size_t)NTOK * IN_DIM;                //   589,824 f16 each
    _Float16* MTl = MTh + (size_t)D_MODEL * D_MODEL;
    // qs pair aliases x pair (x is dead after GEMM1 within each batch iter)
    _Float16* qsh = xh;
    _Float16* qsl = xl;

    // w_qkv split once per call
    split_f32_kernel<<<(OC * IN_DIM / 4 + 255) / 256, 256, 0, stream>>>(
        w_qkv, wqh, wql, OC * IN_DIM / 4);

    for (int b = 0; b < BATCH; ++b) {
        const float* x_b = x + (size_t)b * NTOK * IN_DIM;
        float* out_b = out + (size_t)b * NTOK * D_MODEL;

        // 0) split x_b into f16 hi/lo
        split_f32_kernel<<<2048, 256, 0, stream>>>(x_b, xh, xl, NTOK * IN_DIM / 4);

        // 1) qkv_b = x_b @ w_qkv^T  [4096,2304]  (split-f16 MFMA, XCD-swizzled 1D grid)
        gemm_nt_f16pair<false><<<(OC / 128) * 32, 256, 0, stream>>>(
            xh, xl, wqh, wql, nullptr, qkv_b, NTOK, IN_DIM, OC);

        // 2) partial contexts + column-sum partials (no atomics)
        dim3 g2(NHEAD, NCH);
        context_kernel<<<g2, 256, 0, stream>>>(qkv_b, ctxp, csp);

        // 2b) reduce partials -> ctx
        reduce_ctx_kernel<<<NHEAD * DH * DH / 256, 256, 0, stream>>>(ctxp, ctx_s);

        // 3) qs = rowwise softmax(q) * SCALE  -> split f16 (overwrites x pair)
        qsoftmax_kernel<<<NTOK, 256, 0, stream>>>(qkv_b, qsh, qsl);

        // 4) MT[o][hd] = sum_e (ctx/colsum) * w_lin  (folds o-projection), split f16
        dim3 g4(NHEAD, D_MODEL / 64);
        mt_kernel<<<g4, 256, 0, stream>>>(ctx_s, csp, w_lin, MTh, MTl);

        // 5) out_b = qs @ MT^T + b_lin  [4096,768]  (split-f16 MFMA, swizzled)
        gemm_nt_f16pair<true><<<(D_MODEL / 128) * 32, 256, 0, stream>>>(
            qsh, qsl, MTh, MTl, b_lin, out_b, NTOK, D_MODEL, D_MODEL);
    }
}